// Round 6
// baseline (85.291 us; speedup 1.0000x reference)
//
#include <hip/hip_runtime.h>
#include <cmath>

#define NV    8     // variables
#define NM    42    // coefficients per variable (degree + p - 1)
#define NK    46    // knots per variable (degree + 2p)
#define TOT_C (NM * NV)   // 336
#define LDS_STRIDE 48     // per-v row stride for sc/sq (NM=42 rounded up)

typedef float f32x4 __attribute__((ext_vector_type(4)));

// ---------------------------------------------------------------------------
// Single fused kernel. Each block redundantly computes the (tiny) parameter
// prep in LDS — softplus, cumsum scan, derivative coefficients — then streams
// its slice of x. Removes the prep kernel launch + stream-dependency bubble
// and the d_ws round-trip (3 KB of L2-hit re-reads per block, free).
//
// Eval: knots are a uniform grid -> cardinal B-spline form.
//   u = (x - t0)/d - k;  y = sum c[k-3+j]*B3_j(u);  dy = sum q[k-3+j]*B2_j(u)
// 4 elements/thread, 16 B/lane global I/O, LDS transposed to s[v*48 + j] so
// per-element gathers are consecutive (ds_read2-fusable) and bank-uniform.
// ---------------------------------------------------------------------------
__device__ __forceinline__ void eval_one(float xv, int v,
                                         const float* __restrict__ sc,
                                         const float* __restrict__ sq,
                                         const float* __restrict__ st0,
                                         const float* __restrict__ sinvd,
                                         float& yv, float& ldv) {
    float f = (xv - st0[v]) * sinvd[v];
    int k = (int)floorf(f);
    k = min(max(k, 3), NK - 5);          // clip to [p, K-p-2] = [3, 41]
    float u = f - (float)k;              // outside [0,1) only when clamped:
                                         // same polynomial extrapolation as deBoor
    int base = v * LDS_STRIDE + (k - 3);
    float c0 = sc[base], c1 = sc[base + 1], c2 = sc[base + 2], c3 = sc[base + 3];
    float q0 = sq[base], q1 = sq[base + 1], q2 = sq[base + 2];

    float omu = 1.f - u;
    float u2 = u * u,  o2 = omu * omu;
    float u3 = u2 * u, o3 = o2 * omu;
    const float k6 = 0.16666666666f;
    float B0 = o3 * k6;
    float B3 = u3 * k6;
    float B1 = (3.f * u3 - 6.f * u2 + 4.f) * k6;
    float B2 = 1.f - B0 - B1 - B3;       // partition of unity
    yv = fmaf(B0, c0, fmaf(B1, c1, fmaf(B2, c2, B3 * c3)));

    float w0 = 0.5f * o2, w2 = 0.5f * u2, w1 = 1.f - w0 - w2;
    ldv = __logf(fmaf(w0, q0, fmaf(w1, q1, w2 * q2)));
}

__global__ __launch_bounds__(256) void fused_kernel(
        const float* __restrict__ x,
        const float* __restrict__ raw,
        const float* __restrict__ knots,
        float* __restrict__ y_out,
        float* __restrict__ ld_out,
        int total) {
    __shared__ float sc[NV * LDS_STRIDE];
    __shared__ float sq[NV * LDS_STRIDE];
    __shared__ float st0[NV];
    __shared__ float sinvd[NV];
    int tid = threadIdx.x;

    // --- inline prep: softplus into transposed LDS ---
    for (int idx = tid; idx < TOT_C; idx += 256) {
        int j = idx >> 3, v = idx & 7;
        float r = raw[idx];
        float inc;
        if (j == 0) {
            inc = r;                      // first row: no softplus
        } else {
            inc = (r > 0.f) ? (r + log1pf(expf(-r))) : log1pf(expf(r));
        }
        sc[v * LDS_STRIDE + j] = inc;
    }
    if (tid < NV) {
        float t0 = knots[tid];
        st0[tid] = t0;
        sinvd[tid] = 1.0f / (knots[NV + tid] - t0);
    }
    __syncthreads();

    // --- Hillis-Steele inclusive scan over j (per v), in transposed layout ---
    for (int off = 1; off < NM; off <<= 1) {
        float val0 = 0.f, val1 = 0.f;
        int idx0 = tid, idx1 = tid + 256;
        if (idx0 < TOT_C) {
            int j = idx0 >> 3, v = idx0 & 7;
            float s = sc[v * LDS_STRIDE + j];
            val0 = s + ((j >= off) ? sc[v * LDS_STRIDE + j - off] : 0.f);
        }
        if (idx1 < TOT_C) {
            int j = idx1 >> 3, v = idx1 & 7;
            float s = sc[v * LDS_STRIDE + j];
            val1 = s + ((j >= off) ? sc[v * LDS_STRIDE + j - off] : 0.f);
        }
        __syncthreads();
        if (idx0 < TOT_C) { int j = idx0 >> 3, v = idx0 & 7; sc[v * LDS_STRIDE + j] = val0; }
        if (idx1 < TOT_C) { int j = idx1 >> 3, v = idx1 & 7; sc[v * LDS_STRIDE + j] = val1; }
        __syncthreads();
    }

    // --- derivative coefficients q[j] = 3*(c[j+1]-c[j]) / (t[j+4]-t[j+1]) ---
    for (int idx = tid; idx < TOT_C; idx += 256) {
        int j = idx >> 3, v = idx & 7;
        float qj = 0.f;                  // j = NM-1 padding, never read
        if (j < NM - 1) {
            float cj = sc[v * LDS_STRIDE + j];
            float cn = sc[v * LDS_STRIDE + j + 1];
            qj = 3.f * (cn - cj) / (knots[(j + 4) * NV + v] - knots[(j + 1) * NV + v]);
        }
        sq[v * LDS_STRIDE + j] = qj;
    }
    __syncthreads();

    // --- streaming eval, 4 elements/thread ---
    int t = blockIdx.x * 256 + tid;
    int i0 = t * 4;
    if (i0 + 3 < total) {
        f32x4 xv = *(const f32x4*)(x + i0);
        int v0 = i0 & (NV - 1);
        float y0, y1, y2, y3, l0, l1, l2, l3;
        eval_one(xv.x, v0,     sc, sq, st0, sinvd, y0, l0);
        eval_one(xv.y, v0 + 1, sc, sq, st0, sinvd, y1, l1);
        eval_one(xv.z, v0 + 2, sc, sq, st0, sinvd, y2, l2);
        eval_one(xv.w, v0 + 3, sc, sq, st0, sinvd, y3, l3);
        f32x4 yv = {y0, y1, y2, y3};
        f32x4 lv = {l0, l1, l2, l3};
        __builtin_nontemporal_store(yv, (f32x4*)(y_out + i0));
        __builtin_nontemporal_store(lv, (f32x4*)(ld_out + i0));
    } else {
        for (int i = i0; i < total; ++i) {
            float yv, lv;
            eval_one(x[i], i & (NV - 1), sc, sq, st0, sinvd, yv, lv);
            y_out[i]  = yv;
            ld_out[i] = lv;
        }
    }
}

extern "C" void kernel_launch(void* const* d_in, const int* in_sizes, int n_in,
                              void* d_out, int out_size, void* d_ws, size_t ws_size,
                              hipStream_t stream) {
    const float* x     = (const float*)d_in[0];
    const float* raw   = (const float*)d_in[1];
    const float* knots = (const float*)d_in[2];

    int total = in_sizes[0];             // N*V = 4,000,000
    float* y_out  = (float*)d_out;
    float* ld_out = y_out + total;

    int nthreads = (total + 3) / 4;
    int blocks = (nthreads + 255) / 256;
    fused_kernel<<<blocks, 256, 0, stream>>>(x, raw, knots, y_out, ld_out, total);
}

// Round 7
// 81.996 us; speedup vs baseline: 1.0402x; 1.0402x over previous
//
#include <hip/hip_runtime.h>
#include <cmath>

#define NV    8     // variables
#define NM    42    // coefficients per variable (degree + p - 1)
#define NK    46    // knots per variable (degree + 2p)
#define TOT_C (NM * NV)   // 336
#define LDS_STRIDE 48     // per-v row stride for sc (NM=42 rounded up)

typedef float f32x4 __attribute__((ext_vector_type(4)));

// ---------------------------------------------------------------------------
// Prep (parallel, one tiny block): incr = [raw[0], softplus(raw[1:])];
// c = cumsum(incr) via Hillis-Steele scan in LDS. No q needed: on the uniform
// knot grid q_j = 3(c_{j+1}-c_j)/(t_{j+4}-t_{j+1}) = (c_{j+1}-c_j)/d, which
// eval reconstructs from the c values it already fetched.
// ---------------------------------------------------------------------------
__global__ void prep_kernel(const float* __restrict__ raw,
                            float* __restrict__ c) {
    __shared__ float s[TOT_C];
    int tid = threadIdx.x;
    if (tid < TOT_C) {
        float r = raw[tid];
        float inc;
        if (tid < NV) {
            inc = r;                      // first row: no softplus
        } else {
            inc = (r > 0.f) ? (r + log1pf(expf(-r))) : log1pf(expf(r));
        }
        s[tid] = inc;
    }
    __syncthreads();
    for (int off = 1; off < NM; off <<= 1) {
        float val = 0.f;
        if (tid < TOT_C) {
            int j = tid >> 3;
            val = s[tid] + ((j >= off) ? s[tid - off * NV] : 0.f);
        }
        __syncthreads();
        if (tid < TOT_C) s[tid] = val;
        __syncthreads();
    }
    if (tid < TOT_C) c[tid] = s[tid];
}

// ---------------------------------------------------------------------------
// Eval: uniform knots -> cardinal B-spline form.
//   u = (x - t0)/d - k
//   y  = c0*B0 + c1*B1 + c2*B2 + c3*B3          (uniform cubic basis)
//   dy = (w0*(c1-c0) + w1*(c2-c1) + w2*(c3-c2)) / d   (uniform quadratic on
//        the finite differences -- q array eliminated)
// 8 elements/thread = one full v=0..7 group: v is compile-time per slot,
// st0/sinvd reads are same-address broadcasts, wave count halves.
// LDS sc transposed to [v*48 + j]: per-element gathers consecutive
// (ds_read2-fusable), banks (16v+k)%32 uniform under random k.
// ---------------------------------------------------------------------------
template <int V>
__device__ __forceinline__ void eval_one(float xv,
                                         const float* __restrict__ sc,
                                         const float* __restrict__ st0,
                                         const float* __restrict__ sinvd,
                                         float& yv, float& ldv) {
    float invd = sinvd[V];
    float f = (xv - st0[V]) * invd;
    int k = (int)floorf(f);
    k = min(max(k, 3), NK - 5);          // clip to [p, K-p-2] = [3, 41]
    float u = f - (float)k;              // outside [0,1) only when clamped:
                                         // same polynomial extrapolation as deBoor
    int base = V * LDS_STRIDE + (k - 3);
    float c0 = sc[base], c1 = sc[base + 1], c2 = sc[base + 2], c3 = sc[base + 3];

    float omu = 1.f - u;
    float u2 = u * u,  o2 = omu * omu;
    float u3 = u2 * u, o3 = o2 * omu;
    const float k6 = 0.16666666666f;
    float B0 = o3 * k6;
    float B3 = u3 * k6;
    float B1 = (3.f * u3 - 6.f * u2 + 4.f) * k6;
    float B2 = 1.f - B0 - B1 - B3;       // partition of unity
    yv = fmaf(B0, c0, fmaf(B1, c1, fmaf(B2, c2, B3 * c3)));

    float w0 = 0.5f * o2, w2 = 0.5f * u2, w1 = 1.f - w0 - w2;
    float dy = fmaf(w0, c1 - c0, fmaf(w1, c2 - c1, w2 * (c3 - c2))) * invd;
    ldv = __logf(dy);
}

__global__ __launch_bounds__(256) void eval_kernel(
        const float* __restrict__ x,
        const float* __restrict__ knots,
        const float* __restrict__ c,
        float* __restrict__ y_out,
        float* __restrict__ ld_out,
        int total) {
    __shared__ float sc[NV * LDS_STRIDE];
    __shared__ float st0[NV];
    __shared__ float sinvd[NV];
    int tid = threadIdx.x;
    for (int idx = tid; idx < TOT_C; idx += 256) {
        int j = idx >> 3, v = idx & 7;
        sc[v * LDS_STRIDE + j] = c[idx];
    }
    if (tid < NV) {
        float t0 = knots[tid];
        st0[tid] = t0;
        sinvd[tid] = 1.0f / (knots[NV + tid] - t0);
    }
    __syncthreads();

    int t = blockIdx.x * 256 + tid;
    int i0 = t * 8;                      // i0 % 8 == 0  ->  v = slot index
    if (i0 + 7 < total) {
        f32x4 xa = __builtin_nontemporal_load((const f32x4*)(x + i0));
        f32x4 xb = __builtin_nontemporal_load((const f32x4*)(x + i0 + 4));
        float y0,y1,y2,y3,y4,y5,y6,y7, l0,l1,l2,l3,l4,l5,l6,l7;
        eval_one<0>(xa.x, sc, st0, sinvd, y0, l0);
        eval_one<1>(xa.y, sc, st0, sinvd, y1, l1);
        eval_one<2>(xa.z, sc, st0, sinvd, y2, l2);
        eval_one<3>(xa.w, sc, st0, sinvd, y3, l3);
        eval_one<4>(xb.x, sc, st0, sinvd, y4, l4);
        eval_one<5>(xb.y, sc, st0, sinvd, y5, l5);
        eval_one<6>(xb.z, sc, st0, sinvd, y6, l6);
        eval_one<7>(xb.w, sc, st0, sinvd, y7, l7);
        f32x4 ya = {y0, y1, y2, y3}, yb = {y4, y5, y6, y7};
        f32x4 la = {l0, l1, l2, l3}, lb = {l4, l5, l6, l7};
        __builtin_nontemporal_store(ya, (f32x4*)(y_out + i0));
        __builtin_nontemporal_store(yb, (f32x4*)(y_out + i0 + 4));
        __builtin_nontemporal_store(la, (f32x4*)(ld_out + i0));
        __builtin_nontemporal_store(lb, (f32x4*)(ld_out + i0 + 4));
    } else {
        for (int i = i0; i < total; ++i) {
            // generic-v scalar tail (total % 8 == 0 in practice: never taken)
            int v = i & 7;
            float invd = sinvd[v];
            float f = (x[i] - st0[v]) * invd;
            int k = (int)floorf(f);
            k = min(max(k, 3), NK - 5);
            float u = f - (float)k;
            int base = v * LDS_STRIDE + (k - 3);
            float c0 = sc[base], c1 = sc[base + 1], c2 = sc[base + 2], c3 = sc[base + 3];
            float omu = 1.f - u;
            float u2 = u * u,  o2 = omu * omu;
            float u3 = u2 * u, o3 = o2 * omu;
            const float k6 = 0.16666666666f;
            float B0 = o3 * k6, B3 = u3 * k6;
            float B1 = (3.f * u3 - 6.f * u2 + 4.f) * k6;
            float B2 = 1.f - B0 - B1 - B3;
            y_out[i] = fmaf(B0, c0, fmaf(B1, c1, fmaf(B2, c2, B3 * c3)));
            float w0 = 0.5f * o2, w2 = 0.5f * u2, w1 = 1.f - w0 - w2;
            ld_out[i] = __logf(fmaf(w0, c1 - c0, fmaf(w1, c2 - c1, w2 * (c3 - c2))) * invd);
        }
    }
}

extern "C" void kernel_launch(void* const* d_in, const int* in_sizes, int n_in,
                              void* d_out, int out_size, void* d_ws, size_t ws_size,
                              hipStream_t stream) {
    const float* x     = (const float*)d_in[0];
    const float* raw   = (const float*)d_in[1];
    const float* knots = (const float*)d_in[2];

    float* c = (float*)d_ws;             // 336 floats

    int total = in_sizes[0];             // N*V = 4,000,000
    float* y_out  = (float*)d_out;
    float* ld_out = y_out + total;

    prep_kernel<<<1, 384, 0, stream>>>(raw, c);
    int nthreads = (total + 7) / 8;
    int blocks = (nthreads + 255) / 256;
    eval_kernel<<<blocks, 256, 0, stream>>>(x, knots, c, y_out, ld_out, total);
}